// Round 15
// baseline (835.329 us; speedup 1.0000x reference)
//
#include <hip/hip_runtime.h>

typedef unsigned short u16;
typedef __bf16 bf16x8 __attribute__((ext_vector_type(8)));
typedef float f32x4 __attribute__((ext_vector_type(4)));

#define Bsz 64
#define Ssz 64
#define Tsz 32
#define Hsz 512
#define Vsz 32000
#define NCONV 160
#define NTOT 256

// flag slot families (slot = 128B = 32 u32); plain array (contention disproven r13)
// FH: slot (g*4+m)        : h-tile (g, mtile m) for step t stored -> value t+1
// FW: slot 128 + g*4+i    : Wh-tile (g, mtile i) for step t stored -> value t+1
// FC: slot 256 + b        : ctx_t for batch b stored -> value t+1
#define FW_BASE 128
#define FC_BASE 256
#define NSLOT 320

static __device__ inline u16 f2bf(float f) {
    union { float f; unsigned u; } v; v.f = f;
    unsigned u = v.u;
    unsigned r = (u + 0x7FFFu + ((u >> 16) & 1u)) >> 16;
    return (u16)r;
}
static __device__ inline float bf2f(u16 v) {
    union { unsigned u; float f; } x; x.u = ((unsigned)v) << 16; return x.f;
}
static __device__ inline float tanh_fast(float x) {
    float e = __expf(2.f * x);
    return 1.f - 2.f / (e + 1.f);
}
static __device__ inline void st_u32(unsigned* p, unsigned v) {
    __hip_atomic_store(p, v, __ATOMIC_RELAXED, __HIP_MEMORY_SCOPE_AGENT);
}
static __device__ inline unsigned ld_u32(const unsigned* p) {
    return __hip_atomic_load(p, __ATOMIC_RELAXED, __HIP_MEMORY_SCOPE_AGENT);
}
static __device__ inline uint4 pack8(float4 a, float4 b) {
    uint4 o;
    o.x = (unsigned)f2bf(a.x) | ((unsigned)f2bf(a.y) << 16);
    o.y = (unsigned)f2bf(a.z) | ((unsigned)f2bf(a.w) << 16);
    o.z = (unsigned)f2bf(b.x) | ((unsigned)f2bf(b.y) << 16);
    o.w = (unsigned)f2bf(b.z) | ((unsigned)f2bf(b.w) << 16);
    return o;
}

#define GLOAD_LDS16(g, l) \
    __builtin_amdgcn_global_load_lds((const __attribute__((address_space(1))) void*)(g), \
                                     (__attribute__((address_space(3))) void*)(l), 16, 0, 0)

// ---------------- prep: enc/Ua/Wa/h0 bf16 + embedding gather ----------------
__global__ void prep_kernel(const float* __restrict__ enc, const float* __restrict__ Ua,
                            const float* __restrict__ Wa, const float* __restrict__ ehid,
                            const int* __restrict__ target, const float* __restrict__ emb,
                            u16* __restrict__ encbf, u16* __restrict__ Uabf,
                            u16* __restrict__ Wabf, u16* __restrict__ h0bf,
                            u16* __restrict__ xbuf) {
    const int n0 = 2097152, n1 = 262144, n2 = 262144, n5 = 32768;
    const int n6 = Tsz * Bsz * Hsz;
    const int total = n0 + n1 + n2 + n5 + n6;
    for (int i = blockIdx.x * blockDim.x + threadIdx.x; i < total; i += gridDim.x * blockDim.x) {
        int j = i;
        if (j < n0) { encbf[j] = f2bf(enc[j]); continue; } j -= n0;
        if (j < n1) { Uabf[j] = f2bf(Ua[j]); continue; } j -= n1;
        if (j < n2) { Wabf[j] = f2bf(Wa[j]); continue; } j -= n2;
        if (j < n5) { h0bf[j] = f2bf(ehid[j]); continue; } j -= n5;
        {
            int t = j / (Bsz * Hsz);
            int rem = j % (Bsz * Hsz);
            int b = rem / Hsz, k = rem % Hsz;
            int id = (t == 0) ? 0 : target[b * Tsz + (t - 1)];
            xbuf[((size_t)t * Bsz + b) * 1024 + k] = f2bf(emb[(size_t)id * Hsz + k]);
        }
    }
}

// ---------------- bf16 MFMA GEMM (Ua_keys only) ----------------
__global__ __launch_bounds__(256) void gemm_bt(const u16* __restrict__ A, const u16* __restrict__ Bw,
                                               const float* __restrict__ bias, float* __restrict__ out,
                                               int M, int N, int K) {
    __shared__ __align__(16) u16 As[128 * 32];
    __shared__ __align__(16) u16 Bs[128 * 32];
    int m0 = blockIdx.x * 128, n0 = blockIdx.y * 128;
    int tid = threadIdx.x, lane = tid & 63, wid = tid >> 6;
    int wm = wid & 1, wn = wid >> 1;
    f32x4 acc[4][4] = {};
    for (int k0 = 0; k0 < K; k0 += 32) {
        int e0 = wid * 64 + lane;
        int e1 = e0 + 256;
        GLOAD_LDS16(&A[(size_t)(m0 + (e0 >> 2)) * K + k0 + (e0 & 3) * 8], (char*)As + wid * 1024);
        GLOAD_LDS16(&A[(size_t)(m0 + (e1 >> 2)) * K + k0 + (e1 & 3) * 8], (char*)As + 4096 + wid * 1024);
        GLOAD_LDS16(&Bw[(size_t)(n0 + (e0 >> 2)) * K + k0 + (e0 & 3) * 8], (char*)Bs + wid * 1024);
        GLOAD_LDS16(&Bw[(size_t)(n0 + (e1 >> 2)) * K + k0 + (e1 & 3) * 8], (char*)Bs + 4096 + wid * 1024);
        __syncthreads();
        bf16x8 av[4], bvv[4];
        for (int mi = 0; mi < 4; ++mi)
            av[mi] = *(const bf16x8*)&As[(wm * 64 + mi * 16 + (lane & 15)) * 32 + (lane >> 4) * 8];
        for (int ni = 0; ni < 4; ++ni)
            bvv[ni] = *(const bf16x8*)&Bs[(wn * 64 + ni * 16 + (lane & 15)) * 32 + (lane >> 4) * 8];
        for (int mi = 0; mi < 4; ++mi)
            for (int ni = 0; ni < 4; ++ni)
                acc[mi][ni] = __builtin_amdgcn_mfma_f32_16x16x32_bf16(av[mi], bvv[ni], acc[mi][ni], 0, 0, 0);
        __syncthreads();
    }
    for (int mi = 0; mi < 4; ++mi)
        for (int ni = 0; ni < 4; ++ni) {
            int n = n0 + wn * 64 + ni * 16 + (lane & 15);
            float bb = bias[n];
            for (int r = 0; r < 4; ++r) {
                int m = m0 + wm * 64 + mi * 16 + (lane >> 4) * 4 + r;
                out[(size_t)m * N + n] = acc[mi][ni][r] + bb;
            }
        }
}

// ---------------- persistent recurrence kernel (wave-role split, per-wave flags) ----------------
// blocks 0..63  ("B"): stage uak[b]+enc[b] bf16 LDS; per step: poll FW -> read Wh ->
//                      attention -> ctx store -> FC flag. att stashed in LDS.
// blocks 64..95 ("G"): weights LDS (inline f32->bf16, swizzled). NO block barriers in loop.
//   waves 0..3 (m): emb-MFMA -> poll FH(*,m)>=t -> whh-MFMA -> poll FC>=t+1 ->
//                   ctx-MFMA -> gates -> h store -> per-wave drain -> FH(g,m)=t+1
//   waves 4..7 (i=wid-4): Wa frags in regs; poll FH(*,i)>=t -> 16 MFMA Wh ->
//                   Wh store (bf16 packed) -> per-wave drain -> FW(g,i)=t+1
// blocks 96..255: convert Wo f32->bf16, exit.
__global__ __launch_bounds__(512, 1) void coop_kernel(
    const float* __restrict__ uak,
    u16* __restrict__ xbuf, u16* __restrict__ Abf,
    const u16* __restrict__ h0bf,
    const float* __restrict__ wih, const float* __restrict__ whh,
    const u16* __restrict__ Wabf, const float* __restrict__ enc,
    const float* __restrict__ va, const float* __restrict__ bv, const float* __restrict__ ba,
    const float* __restrict__ b_ih, const float* __restrict__ b_hh,
    const float* __restrict__ ehid,
    const float* __restrict__ Wo, u16* __restrict__ Wobf,
    float* __restrict__ out, unsigned* __restrict__ WhbU,
    unsigned* __restrict__ bar) {
    __shared__ __align__(16) char lds[147456];
    __shared__ float WhL[512];
    __shared__ float scL[64];
    __shared__ float vaL[512];

    const size_t HID_OFF = (size_t)Bsz * Tsz * Vsz;
    const size_t ATT_OFF = HID_OFF + (size_t)Bsz * Hsz;

    int tid = threadIdx.x, lane = tid & 63, wid = tid >> 6;
    int ln15 = lane & 15, hi = lane >> 4;
    int bx = blockIdx.x;

    unsigned* xbufU = (unsigned*)xbuf;
    unsigned* AbfU = (unsigned*)Abf;

    if (bx < 64) {
        // ================= B-blocks =================
        int b = bx;
        int mtile = b >> 4;
        u16* uakL = (u16*)lds;
        u16* encL = (u16*)(lds + 65536);
        float* attL = (float*)(lds + 131072);   // 8 KB att stash
        for (int i = tid; i < Ssz * Hsz; i += 512) {
            uakL[i] = f2bf(uak[(size_t)b * Ssz * Hsz + i]);
            encL[i] = f2bf(enc[(size_t)b * Ssz * Hsz + i]);
        }
        vaL[tid] = va[tid];
        float bvv = bv[0];
        float ba_t = ba[tid];
        int halfsel = tid & 1;
        __syncthreads();

        for (int t = 0; t < Tsz; ++t) {
            if (tid < 32) {
                unsigned* p = &bar[(FW_BASE + tid * 4 + mtile) * 32];
                while (ld_u32(p) < (unsigned)(t + 1)) asm volatile("s_sleep 1");
            }
            __syncthreads();
            {
                unsigned pw = ld_u32(&WhbU[(size_t)t * 16384 + b * 256 + (tid >> 1)]);
                WhL[tid] = bf2f((u16)(halfsel ? (pw >> 16) : (pw & 0xffff))) + ba_t;
            }
            __syncthreads();
            for (int si = 0; si < 8; ++si) {
                int s = wid * 8 + si;
                float a = 0.f;
#pragma unroll
                for (int ji = 0; ji < 8; ++ji) {
                    int j = lane + ji * 64;
                    float x = WhL[j] + bf2f(uakL[s * 512 + j]);
                    a += tanh_fast(x) * vaL[j];
                }
                for (int off = 32; off; off >>= 1) a += __shfl_down(a, off);
                if (lane == 0) scL[s] = a + bvv;
            }
            __syncthreads();
            if (wid == 0) {
                float x = scL[lane];
                float mx = x;
                for (int off = 32; off; off >>= 1) mx = fmaxf(mx, __shfl_xor(mx, off));
                float e = __expf(x - mx);
                float sm = e;
                for (int off = 32; off; off >>= 1) sm += __shfl_xor(sm, off);
                float at = e / sm;
                scL[lane] = at;
                attL[t * 64 + lane] = at;
            }
            __syncthreads();
            float c = 0.f;
            for (int s = 0; s < Ssz; ++s)
                c += scL[s] * bf2f(encL[s * 512 + tid]);
            unsigned me = (unsigned)f2bf(c);
            unsigned other = __shfl_xor(me, 1);
            if ((tid & 1) == 0)
                st_u32(&xbufU[((size_t)t * Bsz + b) * 512 + 256 + (tid >> 1)], me | (other << 16));
            asm volatile("s_waitcnt vmcnt(0)" ::: "memory");
            __syncthreads();
            if (tid == 0) st_u32(&bar[(FC_BASE + b) * 32], (unsigned)(t + 1));
        }
        __syncthreads();
        for (int i = tid; i < Tsz * Ssz; i += 512)
            out[ATT_OFF + (size_t)b * (Tsz * Ssz) + i] = attL[i];
    } else if (bx < 96) {
        // ================= G-blocks =================
        int g = bx - 64, jbase = g * 16;
        // inline f32->bf16 weight staging (swizzled)
        for (int i = tid; i < 6144; i += 512) {
            int row = i >> 7, c16 = i & 127;
            int Rg = (row >> 4) * 512 + jbase + (row & 15);
            const float* src = &wih[(size_t)Rg * 1024 + c16 * 8];
            float4 v0 = *(const float4*)src;
            float4 v1 = *(const float4*)(src + 4);
            *(uint4*)(lds + row * 2048 + ((c16 * 16) ^ ((row & 7) << 4))) = pack8(v0, v1);
        }
        for (int i = tid; i < 3072; i += 512) {
            int row = i >> 6, c16 = i & 63;
            int Rg = (row >> 4) * 512 + jbase + (row & 15);
            const float* src = &whh[(size_t)Rg * 512 + c16 * 8];
            float4 v0 = *(const float4*)src;
            float4 v1 = *(const float4*)(src + 4);
            *(uint4*)(lds + 98304 + row * 1024 + ((c16 * 16) ^ ((row & 7) << 4))) = pack8(v0, v1);
        }
        __syncthreads();   // weights visible to all waves; no more block barriers

        if (wid >= 4) {
            // ---------- Wh waves ----------
            int i = wid - 4;
            bf16x8 wfragW[16];
#pragma unroll
            for (int k0 = 0; k0 < 16; ++k0)
                wfragW[k0] = *(const bf16x8*)&Wabf[(size_t)(jbase + ln15) * 512 + k0 * 32 + hi * 8];
            for (int t = 0; t < Tsz; ++t) {
                const u16* hbt = t ? (Abf + (size_t)(t - 1) * Bsz * Hsz) : h0bf;
                if (t) {
                    unsigned* p = &bar[((lane & 31) * 4 + i) * 32];
                    while (ld_u32(p) < (unsigned)t) asm volatile("s_sleep 1");
                }
                f32x4 accW = {};
#pragma unroll
                for (int k0 = 0; k0 < 16; ++k0) {
                    bf16x8 a = *(const bf16x8*)&hbt[(size_t)(i * 16 + ln15) * 512 + k0 * 32 + hi * 8];
                    accW = __builtin_amdgcn_mfma_f32_16x16x32_bf16(a, wfragW[k0], accW, 0, 0, 0);
                }
                unsigned* WhT = WhbU + (size_t)t * 16384;
#pragma unroll
                for (int r = 0; r < 4; ++r) {
                    unsigned me = (unsigned)f2bf(accW[r]);
                    unsigned other = __shfl_xor(me, 1);
                    if ((ln15 & 1) == 0)
                        st_u32(&WhT[(i * 16 + hi * 4 + r) * 256 + ((jbase + ln15) >> 1)], me | (other << 16));
                }
                asm volatile("s_waitcnt vmcnt(0)" ::: "memory");
                if (lane == 0) st_u32(&bar[(FW_BASE + g * 4 + i) * 32], (unsigned)(t + 1));
            }
        } else {
            // ---------- compute waves ----------
            int m = wid;
            const char* wih_l = lds;
            const char* whh_l = lds + 98304;
            int j = jbase + ln15;
            float bir = b_ih[j] + b_hh[j];
            float biz = b_ih[512 + j] + b_hh[512 + j];
            float bin = b_ih[1024 + j];
            float bhn = b_hh[1024 + j];
            float hp0 = ehid[(size_t)(m * 16 + hi * 4 + 0) * Hsz + j];
            float hp1 = ehid[(size_t)(m * 16 + hi * 4 + 1) * Hsz + j];
            float hp2 = ehid[(size_t)(m * 16 + hi * 4 + 2) * Hsz + j];
            float hp3 = ehid[(size_t)(m * 16 + hi * 4 + 3) * Hsz + j];
            int swz = (ln15 & 7) << 4;

            for (int t = 0; t < Tsz; ++t) {
                const u16* hbt = t ? (Abf + (size_t)(t - 1) * Bsz * Hsz) : h0bf;
                f32x4 ar = {}, az = {}, ain = {}, ahn = {};
                // emb half (prep data, no deps)
#pragma unroll 8
                for (int k0 = 0; k0 < 16; ++k0) {
                    bf16x8 a = *(const bf16x8*)&xbuf[((size_t)t * Bsz + m * 16 + ln15) * 1024 + k0 * 32 + hi * 8];
                    int byteIn = k0 * 64 + hi * 16;
                    bf16x8 b0 = *(const bf16x8*)(wih_l + (0 + ln15) * 2048 + (byteIn ^ swz));
                    bf16x8 b1 = *(const bf16x8*)(wih_l + (16 + ln15) * 2048 + (byteIn ^ swz));
                    bf16x8 b2 = *(const bf16x8*)(wih_l + (32 + ln15) * 2048 + (byteIn ^ swz));
                    ar = __builtin_amdgcn_mfma_f32_16x16x32_bf16(a, b0, ar, 0, 0, 0);
                    az = __builtin_amdgcn_mfma_f32_16x16x32_bf16(a, b1, az, 0, 0, 0);
                    ain = __builtin_amdgcn_mfma_f32_16x16x32_bf16(a, b2, ain, 0, 0, 0);
                }
                if (t) {
                    unsigned* p = &bar[((lane & 31) * 4 + m) * 32];
                    while (ld_u32(p) < (unsigned)t) asm volatile("s_sleep 1");
                }
#pragma unroll 8
                for (int k0 = 0; k0 < 16; ++k0) {
                    bf16x8 a = *(const bf16x8*)&hbt[(size_t)(m * 16 + ln15) * 512 + k0 * 32 + hi * 8];
                    int byteIn = k0 * 64 + hi * 16;
                    bf16x8 b0 = *(const bf16x8*)(whh_l + (0 + ln15) * 1024 + (byteIn ^ swz));
                    bf16x8 b1 = *(const bf16x8*)(whh_l + (16 + ln15) * 1024 + (byteIn ^ swz));
                    bf16x8 b2 = *(const bf16x8*)(whh_l + (32 + ln15) * 1024 + (byteIn ^ swz));
                    ar = __builtin_amdgcn_mfma_f32_16x16x32_bf16(a, b0, ar, 0, 0, 0);
                    az = __builtin_amdgcn_mfma_f32_16x16x32_bf16(a, b1, az, 0, 0, 0);
                    ahn = __builtin_amdgcn_mfma_f32_16x16x32_bf16(a, b2, ahn, 0, 0, 0);
                }
                {
                    unsigned* p = &bar[(FC_BASE + m * 16 + ln15) * 32];
                    while (ld_u32(p) < (unsigned)(t + 1)) asm volatile("s_sleep 1");
                }
#pragma unroll 8
                for (int k0 = 16; k0 < 32; ++k0) {
                    bf16x8 a = *(const bf16x8*)&xbuf[((size_t)t * Bsz + m * 16 + ln15) * 1024 + k0 * 32 + hi * 8];
                    int byteIn = k0 * 64 + hi * 16;
                    bf16x8 b0 = *(const bf16x8*)(wih_l + (0 + ln15) * 2048 + (byteIn ^ swz));
                    bf16x8 b1 = *(const bf16x8*)(wih_l + (16 + ln15) * 2048 + (byteIn ^ swz));
                    bf16x8 b2 = *(const bf16x8*)(wih_l + (32 + ln15) * 2048 + (byteIn ^ swz));
                    ar = __builtin_amdgcn_mfma_f32_16x16x32_bf16(a, b0, ar, 0, 0, 0);
                    az = __builtin_amdgcn_mfma_f32_16x16x32_bf16(a, b1, az, 0, 0, 0);
                    ain = __builtin_amdgcn_mfma_f32_16x16x32_bf16(a, b2, ain, 0, 0, 0);
                }
                float hpv[4] = {hp0, hp1, hp2, hp3};
#pragma unroll
                for (int r = 0; r < 4; ++r) {
                    int b = m * 16 + hi * 4 + r;
                    float rg = 1.f / (1.f + __expf(-(ar[r] + bir)));
                    float zg = 1.f / (1.f + __expf(-(az[r] + biz)));
                    float ng = tanh_fast(ain[r] + bin + rg * (ahn[r] + bhn));
                    float hv = (1.f - zg) * ng + zg * hpv[r];
                    hpv[r] = hv;
                    unsigned me = (unsigned)f2bf(hv);
                    unsigned other = __shfl_xor(me, 1);
                    if ((ln15 & 1) == 0)
                        st_u32(&AbfU[((size_t)t * Bsz + b) * 256 + (j >> 1)], me | (other << 16));
                    if (t == Tsz - 1) out[HID_OFF + (size_t)b * 512 + j] = hv;
                }
                hp0 = hpv[0]; hp1 = hpv[1]; hp2 = hpv[2]; hp3 = hpv[3];
                asm volatile("s_waitcnt vmcnt(0)" ::: "memory");
                if (lane == 0) st_u32(&bar[(g * 4 + m) * 32], (unsigned)(t + 1));
            }
        }
    } else {
        // ================= converter blocks: Wo f32 -> bf16 =================
        const float4* W4 = (const float4*)Wo;
        for (int i = (bx - 96) * 512 + tid; i < (Vsz * Hsz) / 4; i += NCONV * 512) {
            float4 v = W4[i];
            ushort4 o;
            o.x = f2bf(v.x); o.y = f2bf(v.y); o.z = f2bf(v.z); o.w = f2bf(v.w);
            *(ushort4*)&Wobf[(size_t)i * 4] = o;
        }
    }
}

// ---------------- logits GEMM: 128x256 tiles, dbuf + counted vmcnt ----------------
template <int BF16OUT>
__global__ __launch_bounds__(512) void gemm_logits(const u16* __restrict__ Abf, const u16* __restrict__ Wobf,
                                                   const float* __restrict__ bo, float* __restrict__ out,
                                                   u16* __restrict__ scr, float* __restrict__ sumexp) {
    __shared__ __align__(16) char lds[49152];
    char* As0 = lds;
    char* Bs0 = lds + 8192;
    char* As1 = lds + 24576;
    char* Bs1 = lds + 32768;
    int tid = threadIdx.x, lane = tid & 63, wid = tid >> 6;
    int ln15 = lane & 15, hi = lane >> 4;
    int wm = wid & 1, wn = wid >> 1;
    int job = blockIdx.x;
    int m0 = (job / 125) * 128, n0 = (job % 125) * 256;
    f32x4 acc[4][4] = {};
    {
        int e0 = wid * 64 + lane, r = e0 >> 2, c8 = (e0 & 3) * 8;
        GLOAD_LDS16(&Abf[(size_t)(m0 + r) * 512 + c8], As0 + wid * 1024);
        GLOAD_LDS16(&Wobf[(size_t)(n0 + r) * 512 + c8], Bs0 + wid * 1024);
        GLOAD_LDS16(&Wobf[(size_t)(n0 + 128 + r) * 512 + c8], Bs0 + 8192 + wid * 1024);
    }
#pragma unroll 2
    for (int ks = 0; ks < 16; ++ks) {
        const u16* As = (const u16*)((ks & 1) ? As1 : As0);
        const u16* Bs = (const u16*)((ks & 1) ? Bs1 : Bs0);
        if (ks < 15) {
            char* Asn = (ks & 1) ? As0 : As1;
            char* Bsn = (ks & 1) ? Bs0 : Bs1;
            int e0 = wid * 64 + lane, r = e0 >> 2, c8 = (e0 & 3) * 8;
            int k0 = (ks + 1) * 32;
            GLOAD_LDS16(&Abf[(size_t)(m0 + r) * 512 + k0 + c8], Asn + wid * 1024);
            GLOAD_LDS16(&Wobf[(size_t)(n0 + r) * 512 + k0 + c8], Bsn + wid * 1024);
            GLOAD_LDS16(&Wobf[(size_t)(n0 + 128 + r) * 512 + k0 + c8], Bsn + 8192 + wid * 1024);
            asm volatile("s_waitcnt vmcnt(3)" ::: "memory");
        } else {
            asm volatile("s_waitcnt vmcnt(0)" ::: "memory");
        }
        __builtin_amdgcn_s_barrier();
        bf16x8 av[4], bvv[4];
        for (int mi = 0; mi < 4; ++mi)
            av[mi] = *(const bf16x8*)&As[(wm * 64 + mi * 16 + ln15) * 32 + hi * 8];
        for (int ni = 0; ni < 4; ++ni)
            bvv[ni] = *(const bf16x8*)&Bs[(wn * 64 + ni * 16 + ln15) * 32 + hi * 8];
        for (int mi = 0; mi < 4; ++mi)
            for (int ni = 0; ni < 4; ++ni)
                acc[mi][ni] = __builtin_amdgcn_mfma_f32_16x16x32_bf16(av[mi], bvv[ni], acc[mi][ni], 0, 0, 0);
        asm volatile("s_waitcnt lgkmcnt(0)" ::: "memory");
        __builtin_amdgcn_s_barrier();
    }
    float* eps = (float*)lds;
    float bb[4];
#pragma unroll
    for (int ni = 0; ni < 4; ++ni) bb[ni] = bo[n0 + wn * 64 + ni * 16 + ln15];
    for (int mi = 0; mi < 4; ++mi) {
        __syncthreads();
#pragma unroll
        for (int ni = 0; ni < 4; ++ni)
#pragma unroll
            for (int r = 0; r < 4; ++r)
                eps[(wm * 16 + hi * 4 + r) * 256 + wn * 64 + ni * 16 + ln15] = acc[mi][ni][r] + bb[ni];
        __syncthreads();
#pragma unroll
        for (int k = 0; k < 4; ++k) {
            int idx = k * 512 + tid;
            int l = idx >> 6, c4 = idx & 63;
            int m = m0 + (l >> 4) * 64 + mi * 16 + (l & 15);
            int t = m >> 6, b = m & 63;
            float4 v = *(float4*)&eps[l * 256 + c4 * 4];
            if (BF16OUT) {
                ushort4 o;
                o.x = f2bf(v.x); o.y = f2bf(v.y); o.z = f2bf(v.z); o.w = f2bf(v.w);
                *(ushort4*)&scr[((size_t)(b * Tsz + t)) * Vsz + n0 + c4 * 4] = o;
            } else {
                *(float4*)&out[((size_t)(b * Tsz + t)) * Vsz + n0 + c4 * 4] = v;
            }
            float e = __expf(v.x) + __expf(v.y) + __expf(v.z) + __expf(v.w);
            for (int off = 32; off; off >>= 1) e += __shfl_down(e, off);
            if (lane == 0) atomicAdd(&sumexp[(m & 63) * Tsz + (m >> 6)], e);
        }
    }
}

// ---------------- log-softmax kernels ----------------
__global__ void sub_kernel(float* __restrict__ out, const float* __restrict__ sumexp) {
    const int total4 = (Bsz * Tsz * Vsz) / 4;
    float4* o4 = (float4*)out;
    for (int i = blockIdx.x * blockDim.x + threadIdx.x; i < total4; i += gridDim.x * blockDim.x) {
        float l = __logf(sumexp[i / (Vsz / 4)]);
        float4 v = o4[i];
        v.x -= l; v.y -= l; v.z -= l; v.w -= l;
        o4[i] = v;
    }
}

__global__ void sub_bf16_kernel(const u16* __restrict__ scr, const float* __restrict__ sumexp,
                                float* __restrict__ out) {
    const int total8 = (Bsz * Tsz * Vsz) / 8;
    for (int i = blockIdx.x * blockDim.x + threadIdx.x; i < total8; i += gridDim.x * blockDim.x) {
        float l = __logf(sumexp[i / (Vsz / 8)]);
        uint4 v = *(const uint4*)&scr[(size_t)i * 8];
        float4 a, b;
        a.x = bf2f((u16)v.x) - l;        a.y = bf2f((u16)(v.x >> 16)) - l;
        a.z = bf2f((u16)v.y) - l;        a.w = bf2f((u16)(v.y >> 16)) - l;
        b.x = bf2f((u16)v.z) - l;        b.y = bf2f((u16)(v.z >> 16)) - l;
        b.z = bf2f((u16)v.w) - l;        b.w = bf2f((u16)(v.w >> 16)) - l;
        *(float4*)&out[(size_t)i * 8] = a;
        *(float4*)&out[(size_t)i * 8 + 4] = b;
    }
}

extern "C" void kernel_launch(void* const* d_in, const int* in_sizes, int n_in,
                              void* d_out, int out_size, void* d_ws, size_t ws_size,
                              hipStream_t stream) {
    const float* enc   = (const float*)d_in[0];
    const float* ehid  = (const float*)d_in[1];
    const int*   target= (const int*)d_in[2];
    const float* emb   = (const float*)d_in[3];
    const float* Wa    = (const float*)d_in[4];
    const float* ba    = (const float*)d_in[5];
    const float* Ua    = (const float*)d_in[6];
    const float* bu    = (const float*)d_in[7];
    const float* va    = (const float*)d_in[8];
    const float* bv    = (const float*)d_in[9];
    const float* w_ih  = (const float*)d_in[10];
    const float* b_ih  = (const float*)d_in[11];
    const float* w_hh  = (const float*)d_in[12];
    const float* b_hh  = (const float*)d_in[13];
    const float* Wo    = (const float*)d_in[14];
    const float* bo    = (const float*)d_in[15];
    float* out = (float*)d_out;

    char* w = (char*)d_ws;
    float* uak    = (float*)w; w += (size_t)4096 * 512 * 4;           // 8 MB
    float* sumexp = (float*)w; w += 8192;
    unsigned* bar = (unsigned*)w; w += (size_t)NSLOT * 128;           // 40 KB flags
    unsigned* WhbU= (unsigned*)w; w += (size_t)Tsz * Bsz * 256 * 4;   // 2 MB Wh (bf16 pairs)
    u16* xbuf     = (u16*)w;   w += (size_t)Tsz * Bsz * 1024 * 2;     // 4 MB
    u16* Abf      = (u16*)w;   w += (size_t)Tsz * Bsz * Hsz * 2;      // 2 MB
    u16* h0bf     = (u16*)w;   w += (size_t)Bsz * Hsz * 2;
    u16* Wabf     = (u16*)w;   w += (size_t)Hsz * Hsz * 2;
    u16* encbf    = (u16*)w;   w += (size_t)4096 * 512 * 2;           // 4 MB
    u16* Uabf     = (u16*)w;   w += (size_t)Hsz * Hsz * 2;
    u16* Wobf     = (u16*)w;   w += (size_t)Vsz * 512 * 2;            // 32.77 MB
    u16* scrbf    = (u16*)w;   w += (size_t)Bsz * Tsz * Vsz * 2;      // 131 MB
    const int use_bf16 = (ws_size >= (size_t)(w - (char*)d_ws));

    prep_kernel<<<1024, 256, 0, stream>>>(enc, Ua, Wa, ehid, target, emb,
                                          encbf, Uabf, Wabf, h0bf, xbuf);

    // Ua_keys = enc @ Ua.T + bu   (M=4096, N=512, K=512)
    gemm_bt<<<dim3(32, 4), 256, 0, stream>>>(encbf, Uabf, bu, uak, 4096, 512, 512);

    hipMemsetAsync(bar, 0, (size_t)NSLOT * 128, stream);
    hipMemsetAsync(sumexp, 0, 2048 * 4, stream);

    // recurrence (96 blocks, wave-role split) + Wo conversion (160 blocks)
    coop_kernel<<<NTOT, 512, 0, stream>>>(uak, xbuf, Abf, h0bf, w_ih, w_hh,
                                          Wabf, enc, va, bv, ba, b_ih, b_hh,
                                          ehid, Wo, Wobf, out, WhbU, bar);

    // logits = H @ Wo.T + bo  (M=2048, N=32000, K=512), 128x256 tiles
    if (use_bf16) {
        gemm_logits<1><<<2000, 512, 0, stream>>>(Abf, Wobf, bo, out, scrbf, sumexp);
        sub_bf16_kernel<<<4096, 256, 0, stream>>>(scrbf, sumexp, out);
    } else {
        gemm_logits<0><<<2000, 512, 0, stream>>>(Abf, Wobf, bo, out, scrbf, sumexp);
        sub_kernel<<<2048, 256, 0, stream>>>(out, sumexp);
    }
}

// Round 16
// 807.569 us; speedup vs baseline: 1.0344x; 1.0344x over previous
//
#include <hip/hip_runtime.h>

typedef unsigned short u16;
typedef __bf16 bf16x8 __attribute__((ext_vector_type(8)));
typedef float f32x4 __attribute__((ext_vector_type(4)));

#define Bsz 64
#define Ssz 64
#define Tsz 32
#define Hsz 512
#define Vsz 32000
#define NCONV 160
#define NTOT 256

// mailbox flag regions (slot = 128B = 32 u32)
#define MAIL_BG 0
#define MAIL_GB 2048
#define MAIL_GG 4096
#define NMAIL 5120

static __device__ inline u16 f2bf(float f) {
    union { float f; unsigned u; } v; v.f = f;
    unsigned u = v.u;
    unsigned r = (u + 0x7FFFu + ((u >> 16) & 1u)) >> 16;
    return (u16)r;
}
static __device__ inline float bf2f(u16 v) {
    union { unsigned u; float f; } x; x.u = ((unsigned)v) << 16; return x.f;
}
static __device__ inline float tanh_fast(float x) {
    float e = __expf(2.f * x);
    return 1.f - 2.f / (e + 1.f);
}
static __device__ inline void st_u32(unsigned* p, unsigned v) {
    __hip_atomic_store(p, v, __ATOMIC_RELAXED, __HIP_MEMORY_SCOPE_AGENT);
}
static __device__ inline unsigned ld_u32(const unsigned* p) {
    return __hip_atomic_load(p, __ATOMIC_RELAXED, __HIP_MEMORY_SCOPE_AGENT);
}

#define GLOAD_LDS16(g, l) \
    __builtin_amdgcn_global_load_lds((const __attribute__((address_space(1))) void*)(g), \
                                     (__attribute__((address_space(3))) void*)(l), 16, 0, 0)

// ---------------- prep: weight conversion + embedding + flag/sumexp zeroing ----------------
__global__ void prep_kernel(const float* __restrict__ enc, const float* __restrict__ Ua,
                            const float* __restrict__ Wa, const float* __restrict__ wih,
                            const float* __restrict__ whh, const float* __restrict__ ehid,
                            const int* __restrict__ target, const float* __restrict__ emb,
                            u16* __restrict__ encbf, u16* __restrict__ Uabf,
                            u16* __restrict__ Wabf, u16* __restrict__ wihbf,
                            u16* __restrict__ whhbf, u16* __restrict__ h0bf,
                            u16* __restrict__ xbuf,
                            unsigned* __restrict__ bar, float* __restrict__ sumexp) {
    const int n0 = 2097152, n1 = 262144, n2 = 262144, n3 = 1572864, n4 = 786432, n5 = 32768;
    const int n6 = Tsz * Bsz * Hsz;
    const int n7 = NMAIL * 32;      // bar zeroing (u32 count)
    const int n8 = 2048;            // sumexp zeroing
    const int total = n0 + n1 + n2 + n3 + n4 + n5 + n6 + n7 + n8;
    for (int i = blockIdx.x * blockDim.x + threadIdx.x; i < total; i += gridDim.x * blockDim.x) {
        int j = i;
        if (j < n0) { encbf[j] = f2bf(enc[j]); continue; } j -= n0;
        if (j < n1) { Uabf[j] = f2bf(Ua[j]); continue; } j -= n1;
        if (j < n2) { Wabf[j] = f2bf(Wa[j]); continue; } j -= n2;
        if (j < n3) { wihbf[j] = f2bf(wih[j]); continue; } j -= n3;
        if (j < n4) { whhbf[j] = f2bf(whh[j]); continue; } j -= n4;
        if (j < n5) { h0bf[j] = f2bf(ehid[j]); continue; } j -= n5;
        if (j < n6) {
            int t = j / (Bsz * Hsz);
            int rem = j % (Bsz * Hsz);
            int b = rem / Hsz, k = rem % Hsz;
            int id = (t == 0) ? 0 : target[b * Tsz + (t - 1)];
            xbuf[((size_t)t * Bsz + b) * 1024 + k] = f2bf(emb[(size_t)id * Hsz + k]);
            continue;
        } j -= n6;
        if (j < n7) { bar[j] = 0u; continue; } j -= n7;
        sumexp[j] = 0.f;
    }
}

// ---------------- bf16 MFMA GEMM (Ua_keys only) ----------------
__global__ __launch_bounds__(256) void gemm_bt(const u16* __restrict__ A, const u16* __restrict__ Bw,
                                               const float* __restrict__ bias, float* __restrict__ out,
                                               int M, int N, int K) {
    __shared__ __align__(16) u16 As[128 * 32];
    __shared__ __align__(16) u16 Bs[128 * 32];
    int m0 = blockIdx.x * 128, n0 = blockIdx.y * 128;
    int tid = threadIdx.x, lane = tid & 63, wid = tid >> 6;
    int wm = wid & 1, wn = wid >> 1;
    f32x4 acc[4][4] = {};
    for (int k0 = 0; k0 < K; k0 += 32) {
        int e0 = wid * 64 + lane;
        int e1 = e0 + 256;
        GLOAD_LDS16(&A[(size_t)(m0 + (e0 >> 2)) * K + k0 + (e0 & 3) * 8], (char*)As + wid * 1024);
        GLOAD_LDS16(&A[(size_t)(m0 + (e1 >> 2)) * K + k0 + (e1 & 3) * 8], (char*)As + 4096 + wid * 1024);
        GLOAD_LDS16(&Bw[(size_t)(n0 + (e0 >> 2)) * K + k0 + (e0 & 3) * 8], (char*)Bs + wid * 1024);
        GLOAD_LDS16(&Bw[(size_t)(n0 + (e1 >> 2)) * K + k0 + (e1 & 3) * 8], (char*)Bs + 4096 + wid * 1024);
        __syncthreads();
        bf16x8 av[4], bvv[4];
        for (int mi = 0; mi < 4; ++mi)
            av[mi] = *(const bf16x8*)&As[(wm * 64 + mi * 16 + (lane & 15)) * 32 + (lane >> 4) * 8];
        for (int ni = 0; ni < 4; ++ni)
            bvv[ni] = *(const bf16x8*)&Bs[(wn * 64 + ni * 16 + (lane & 15)) * 32 + (lane >> 4) * 8];
        for (int mi = 0; mi < 4; ++mi)
            for (int ni = 0; ni < 4; ++ni)
                acc[mi][ni] = __builtin_amdgcn_mfma_f32_16x16x32_bf16(av[mi], bvv[ni], acc[mi][ni], 0, 0, 0);
        __syncthreads();
    }
    for (int mi = 0; mi < 4; ++mi)
        for (int ni = 0; ni < 4; ++ni) {
            int n = n0 + wn * 64 + ni * 16 + (lane & 15);
            float bb = bias[n];
            for (int r = 0; r < 4; ++r) {
                int m = m0 + wm * 64 + mi * 16 + (lane >> 4) * 4 + r;
                out[(size_t)m * N + n] = acc[mi][ni][r] + bb;
            }
        }
}

// ---------------- persistent recurrence kernel (round-13 proven form: mailbox + partials) ----
__global__ __launch_bounds__(512, 1) void coop_kernel(
    const float* __restrict__ uak,
    u16* __restrict__ xbuf, u16* __restrict__ Abf,
    const u16* __restrict__ h0bf, const u16* __restrict__ wihbf, const u16* __restrict__ whhbf,
    const u16* __restrict__ Wabf, const float* __restrict__ enc,
    const float* __restrict__ va, const float* __restrict__ bv, const float* __restrict__ ba,
    const float* __restrict__ b_ih, const float* __restrict__ b_hh,
    const float* __restrict__ ehid,
    const float* __restrict__ Wo, u16* __restrict__ Wobf,
    float* __restrict__ out, u16* __restrict__ partials,
    unsigned* __restrict__ bar) {
    __shared__ __align__(16) char lds[149504];
    __shared__ float WhL[512];
    __shared__ float scL[64];
    __shared__ float vaL[512];

    const size_t HID_OFF = (size_t)Bsz * Tsz * Vsz;
    const size_t ATT_OFF = HID_OFF + (size_t)Bsz * Hsz;

    int tid = threadIdx.x, lane = tid & 63, wid = tid >> 6;
    int ln15 = lane & 15, hi = lane >> 4;
    int bx = blockIdx.x;

    unsigned* xbufU = (unsigned*)xbuf;
    unsigned* AbfU = (unsigned*)Abf;
    unsigned* partU = (unsigned*)partials;

    if (bx < 64) {
        // ================= B-blocks: Wh-sum + attention =================
        int b = bx;
        u16* uakL = (u16*)lds;
        u16* encL = (u16*)(lds + 65536);
        float* attL = (float*)(lds + 131072);   // 8 KB att stash
        for (int i = tid; i < Ssz * Hsz; i += 512) {
            uakL[i] = f2bf(uak[(size_t)b * Ssz * Hsz + i]);
            encL[i] = f2bf(enc[(size_t)b * Ssz * Hsz + i]);
        }
        vaL[tid] = va[tid];
        float bvv = bv[0];
        float ba_t = ba[tid];
        int halfsel = tid & 1;
        __syncthreads();

        for (int t = 0; t < Tsz; ++t) {
            if (tid < 32) {
                unsigned* p = &bar[(MAIL_GB + b * 32 + tid) * 32];
                while (ld_u32(p) < (unsigned)(t + 1)) asm volatile("s_sleep 1");
            }
            __syncthreads();
            {
                float acc = ba_t;
                const unsigned* pb = partU + (size_t)b * 256 + (tid >> 1);
#pragma unroll
                for (int g = 0; g < 32; ++g) {
                    unsigned pw = ld_u32(pb + (size_t)g * 16384);
                    acc += bf2f((u16)(halfsel ? (pw >> 16) : (pw & 0xffff)));
                }
                WhL[tid] = acc;
            }
            __syncthreads();
            for (int si = 0; si < 8; ++si) {
                int s = wid * 8 + si;
                float a = 0.f;
#pragma unroll
                for (int ji = 0; ji < 8; ++ji) {
                    int j = lane + ji * 64;
                    float x = WhL[j] + bf2f(uakL[s * 512 + j]);
                    a += tanh_fast(x) * vaL[j];
                }
                for (int off = 32; off; off >>= 1) a += __shfl_down(a, off);
                if (lane == 0) scL[s] = a + bvv;
            }
            __syncthreads();
            if (wid == 0) {
                float x = scL[lane];
                float mx = x;
                for (int off = 32; off; off >>= 1) mx = fmaxf(mx, __shfl_xor(mx, off));
                float e = __expf(x - mx);
                float sm = e;
                for (int off = 32; off; off >>= 1) sm += __shfl_xor(sm, off);
                float at = e / sm;
                scL[lane] = at;
                attL[t * 64 + lane] = at;
            }
            __syncthreads();
            float c = 0.f;
            for (int s = 0; s < Ssz; ++s)
                c += scL[s] * bf2f(encL[s * 512 + tid]);
            unsigned me = (unsigned)f2bf(c);
            unsigned other = __shfl_xor(me, 1);
            if ((tid & 1) == 0)
                st_u32(&xbufU[((size_t)t * Bsz + b) * 512 + 256 + (tid >> 1)], me | (other << 16));
            asm volatile("s_waitcnt vmcnt(0)" ::: "memory");
            __syncthreads();
            if (tid < 32) st_u32(&bar[(MAIL_BG + tid * 64 + b) * 32], (unsigned)(t + 1));
        }
        __syncthreads();
        for (int i = tid; i < Tsz * Ssz; i += 512)
            out[ATT_OFF + (size_t)b * (Tsz * Ssz) + i] = attL[i];
    } else if (bx < 96) {
        // ================= G-blocks: GRU + Wh-partials =================
        int g = bx - 64, jbase = g * 16;
        u16* hsl = (u16*)(lds + 147456);
        for (int i = tid; i < 6144; i += 512) {
            int row = i >> 7, c16 = i & 127;
            int Rg = (row >> 4) * 512 + jbase + (row & 15);
            uint4 v = *(const uint4*)&wihbf[(size_t)Rg * 1024 + c16 * 8];
            *(uint4*)(lds + row * 2048 + ((c16 * 16) ^ ((row & 7) << 4))) = v;
        }
        for (int i = tid; i < 3072; i += 512) {
            int row = i >> 6, c16 = i & 63;
            int Rg = (row >> 4) * 512 + jbase + (row & 15);
            uint4 v = *(const uint4*)&whhbf[(size_t)Rg * 512 + c16 * 8];
            *(uint4*)(lds + 98304 + row * 1024 + ((c16 * 16) ^ ((row & 7) << 4))) = v;
        }
        const char* wih_l = lds;
        const char* whh_l = lds + 98304;
        int j = jbase + ln15;
        float bir = b_ih[j] + b_hh[j];
        float biz = b_ih[512 + j] + b_hh[512 + j];
        float bin = b_ih[1024 + j];
        float bhn = b_hh[1024 + j];
        float hp0 = 0.f, hp1 = 0.f, hp2 = 0.f, hp3 = 0.f;
        if (wid < 4) {
            int m = wid;
            hp0 = ehid[(size_t)(m * 16 + hi * 4 + 0) * Hsz + j];
            hp1 = ehid[(size_t)(m * 16 + hi * 4 + 1) * Hsz + j];
            hp2 = ehid[(size_t)(m * 16 + hi * 4 + 2) * Hsz + j];
            hp3 = ehid[(size_t)(m * 16 + hi * 4 + 3) * Hsz + j];
        }
        int swz = (ln15 & 7) << 4;
        bf16x8 zfr = {};
        bf16x8 wfrag[4];
#pragma unroll
        for (int i = 0; i < 4; ++i) {
            int jp = (wid * 4 + i) * 16 + ln15;
            wfrag[i] = (hi < 2) ? *(const bf16x8*)&Wabf[(size_t)jp * 512 + jbase + hi * 8] : zfr;
        }
        for (int i = tid; i < 1024; i += 512)
            hsl[i] = h0bf[(size_t)(i >> 4) * 512 + jbase + (i & 15)];
        __syncthreads();
#pragma unroll
        for (int mt = 0; mt < 4; ++mt) {
            bf16x8 af = (hi < 2) ? *(const bf16x8*)&hsl[(mt * 16 + ln15) * 16 + hi * 8] : zfr;
#pragma unroll
            for (int i = 0; i < 4; ++i) {
                f32x4 pacc = {};
                pacc = __builtin_amdgcn_mfma_f32_16x16x32_bf16(af, wfrag[i], pacc, 0, 0, 0);
                int n0 = (wid * 4 + i) * 16;
#pragma unroll
                for (int r = 0; r < 4; ++r) {
                    int b = mt * 16 + hi * 4 + r;
                    unsigned me = (unsigned)f2bf(pacc[r]);
                    unsigned other = __shfl_xor(me, 1);
                    if ((ln15 & 1) == 0)
                        st_u32(&partU[((size_t)g * 64 + b) * 256 + ((n0 + ln15) >> 1)], me | (other << 16));
                }
            }
        }
        asm volatile("s_waitcnt vmcnt(0)" ::: "memory");
        __syncthreads();
        if (tid < 64) st_u32(&bar[(MAIL_GB + tid * 32 + g) * 32], 1u);
        else if (tid < 96) st_u32(&bar[(MAIL_GG + (tid - 64) * 32 + g) * 32], 1u);

        for (int t = 0; t < Tsz; ++t) {
            const u16* hbt = t ? (Abf + (size_t)(t - 1) * Bsz * Hsz) : h0bf;
            f32x4 ar = {}, az = {}, ain = {}, ahn = {};
            if (wid < 4) {
                int m = wid;
#pragma unroll 8
                for (int k0 = 0; k0 < 16; ++k0) {
                    bf16x8 a = *(const bf16x8*)&xbuf[((size_t)t * Bsz + m * 16 + ln15) * 1024 + k0 * 32 + hi * 8];
                    int byteIn = k0 * 64 + hi * 16;
                    bf16x8 b0 = *(const bf16x8*)(wih_l + (0 + ln15) * 2048 + (byteIn ^ swz));
                    bf16x8 b1 = *(const bf16x8*)(wih_l + (16 + ln15) * 2048 + (byteIn ^ swz));
                    bf16x8 b2 = *(const bf16x8*)(wih_l + (32 + ln15) * 2048 + (byteIn ^ swz));
                    ar = __builtin_amdgcn_mfma_f32_16x16x32_bf16(a, b0, ar, 0, 0, 0);
                    az = __builtin_amdgcn_mfma_f32_16x16x32_bf16(a, b1, az, 0, 0, 0);
                    ain = __builtin_amdgcn_mfma_f32_16x16x32_bf16(a, b2, ain, 0, 0, 0);
                }
            }
            if (tid < 32) {
                unsigned* p = &bar[(MAIL_GG + g * 32 + tid) * 32];
                while (ld_u32(p) < (unsigned)(t + 1)) asm volatile("s_sleep 1");
            }
            __syncthreads();
            if (wid < 4) {
                int m = wid;
#pragma unroll 8
                for (int k0 = 0; k0 < 16; ++k0) {
                    bf16x8 a = *(const bf16x8*)&hbt[(size_t)(m * 16 + ln15) * 512 + k0 * 32 + hi * 8];
                    int byteIn = k0 * 64 + hi * 16;
                    bf16x8 b0 = *(const bf16x8*)(whh_l + (0 + ln15) * 1024 + (byteIn ^ swz));
                    bf16x8 b1 = *(const bf16x8*)(whh_l + (16 + ln15) * 1024 + (byteIn ^ swz));
                    bf16x8 b2 = *(const bf16x8*)(whh_l + (32 + ln15) * 1024 + (byteIn ^ swz));
                    ar = __builtin_amdgcn_mfma_f32_16x16x32_bf16(a, b0, ar, 0, 0, 0);
                    az = __builtin_amdgcn_mfma_f32_16x16x32_bf16(a, b1, az, 0, 0, 0);
                    ahn = __builtin_amdgcn_mfma_f32_16x16x32_bf16(a, b2, ahn, 0, 0, 0);
                }
                unsigned* p = &bar[(MAIL_BG + g * 64 + wid * 16 + ln15) * 32];
                while (ld_u32(p) < (unsigned)(t + 1)) asm volatile("s_sleep 1");
#pragma unroll 8
                for (int k0 = 16; k0 < 32; ++k0) {
                    bf16x8 a = *(const bf16x8*)&xbuf[((size_t)t * Bsz + m * 16 + ln15) * 1024 + k0 * 32 + hi * 8];
                    int byteIn = k0 * 64 + hi * 16;
                    bf16x8 b0 = *(const bf16x8*)(wih_l + (0 + ln15) * 2048 + (byteIn ^ swz));
                    bf16x8 b1 = *(const bf16x8*)(wih_l + (16 + ln15) * 2048 + (byteIn ^ swz));
                    bf16x8 b2 = *(const bf16x8*)(wih_l + (32 + ln15) * 2048 + (byteIn ^ swz));
                    ar = __builtin_amdgcn_mfma_f32_16x16x32_bf16(a, b0, ar, 0, 0, 0);
                    az = __builtin_amdgcn_mfma_f32_16x16x32_bf16(a, b1, az, 0, 0, 0);
                    ain = __builtin_amdgcn_mfma_f32_16x16x32_bf16(a, b2, ain, 0, 0, 0);
                }
                float hpv[4] = {hp0, hp1, hp2, hp3};
#pragma unroll
                for (int r = 0; r < 4; ++r) {
                    int b = m * 16 + hi * 4 + r;
                    float rg = 1.f / (1.f + __expf(-(ar[r] + bir)));
                    float zg = 1.f / (1.f + __expf(-(az[r] + biz)));
                    float ng = tanh_fast(ain[r] + bin + rg * (ahn[r] + bhn));
                    float hv = (1.f - zg) * ng + zg * hpv[r];
                    hpv[r] = hv;
                    u16 hb = f2bf(hv);
                    unsigned me = (unsigned)hb;
                    unsigned other = __shfl_xor(me, 1);
                    if ((ln15 & 1) == 0)
                        st_u32(&AbfU[((size_t)t * Bsz + b) * 256 + (j >> 1)], me | (other << 16));
                    hsl[b * 16 + ln15] = hb;
                    if (t == Tsz - 1) out[HID_OFF + (size_t)b * 512 + j] = hv;
                }
                hp0 = hpv[0]; hp1 = hpv[1]; hp2 = hpv[2]; hp3 = hpv[3];
            }
            __syncthreads();
#pragma unroll
            for (int mt = 0; mt < 4; ++mt) {
                bf16x8 af = (hi < 2) ? *(const bf16x8*)&hsl[(mt * 16 + ln15) * 16 + hi * 8] : zfr;
#pragma unroll
                for (int i = 0; i < 4; ++i) {
                    f32x4 pacc = {};
                    pacc = __builtin_amdgcn_mfma_f32_16x16x32_bf16(af, wfrag[i], pacc, 0, 0, 0);
                    int n0 = (wid * 4 + i) * 16;
#pragma unroll
                    for (int r = 0; r < 4; ++r) {
                        int b = mt * 16 + hi * 4 + r;
                        unsigned me = (unsigned)f2bf(pacc[r]);
                        unsigned other = __shfl_xor(me, 1);
                        if ((ln15 & 1) == 0)
                            st_u32(&partU[((size_t)g * 64 + b) * 256 + ((n0 + ln15) >> 1)], me | (other << 16));
                    }
                }
            }
            asm volatile("s_waitcnt vmcnt(0)" ::: "memory");
            __syncthreads();
            if (tid < 64) st_u32(&bar[(MAIL_GB + tid * 32 + g) * 32], (unsigned)(t + 2));
            else if (tid < 96) st_u32(&bar[(MAIL_GG + (tid - 64) * 32 + g) * 32], (unsigned)(t + 2));
        }
    } else {
        // ================= converter blocks: Wo f32 -> bf16 (plain stores) =============
        const float4* W4 = (const float4*)Wo;
        for (int i = (bx - 96) * 512 + tid; i < (Vsz * Hsz) / 4; i += NCONV * 512) {
            float4 v = W4[i];
            ushort4 o;
            o.x = f2bf(v.x); o.y = f2bf(v.y); o.z = f2bf(v.z); o.w = f2bf(v.w);
            *(ushort4*)&Wobf[(size_t)i * 4] = o;
        }
    }
}

// ---------------- logits GEMM: 128x256 tiles, dbuf + counted vmcnt,
//                  L2-locality job map: 16 consecutive blocks share one Wo panel ----------------
template <int BF16OUT>
__global__ __launch_bounds__(512) void gemm_logits(const u16* __restrict__ Abf, const u16* __restrict__ Wobf,
                                                   const float* __restrict__ bo, float* __restrict__ out,
                                                   u16* __restrict__ scr, float* __restrict__ sumexp) {
    __shared__ __align__(16) char lds[49152];
    char* As0 = lds;
    char* Bs0 = lds + 8192;
    char* As1 = lds + 24576;
    char* Bs1 = lds + 32768;
    int tid = threadIdx.x, lane = tid & 63, wid = tid >> 6;
    int ln15 = lane & 15, hi = lane >> 4;
    int wm = wid & 1, wn = wid >> 1;
    int job = blockIdx.x;
    int m0 = (job & 15) * 128, n0 = (job >> 4) * 256;   // panel-sharers adjacent
    f32x4 acc[4][4] = {};
    {
        int e0 = wid * 64 + lane, r = e0 >> 2, c8 = (e0 & 3) * 8;
        GLOAD_LDS16(&Abf[(size_t)(m0 + r) * 512 + c8], As0 + wid * 1024);
        GLOAD_LDS16(&Wobf[(size_t)(n0 + r) * 512 + c8], Bs0 + wid * 1024);
        GLOAD_LDS16(&Wobf[(size_t)(n0 + 128 + r) * 512 + c8], Bs0 + 8192 + wid * 1024);
    }
#pragma unroll 2
    for (int ks = 0; ks < 16; ++ks) {
        const u16* As = (const u16*)((ks & 1) ? As1 : As0);
        const u16* Bs = (const u16*)((ks & 1) ? Bs1 : Bs0);
        if (ks < 15) {
            char* Asn = (ks & 1) ? As0 : As1;
            char* Bsn = (ks & 1) ? Bs0 : Bs1;
            int e0 = wid * 64 + lane, r = e0 >> 2, c8 = (e0 & 3) * 8;
            int k0 = (ks + 1) * 32;
            GLOAD_LDS16(&Abf[(size_t)(m0 + r) * 512 + k0 + c8], Asn + wid * 1024);
            GLOAD_LDS16(&Wobf[(size_t)(n0 + r) * 512 + k0 + c8], Bsn + wid * 1024);
            GLOAD_LDS16(&Wobf[(size_t)(n0 + 128 + r) * 512 + k0 + c8], Bsn + 8192 + wid * 1024);
            asm volatile("s_waitcnt vmcnt(3)" ::: "memory");
        } else {
            asm volatile("s_waitcnt vmcnt(0)" ::: "memory");
        }
        __builtin_amdgcn_s_barrier();
        bf16x8 av[4], bvv[4];
        for (int mi = 0; mi < 4; ++mi)
            av[mi] = *(const bf16x8*)&As[(wm * 64 + mi * 16 + ln15) * 32 + hi * 8];
        for (int ni = 0; ni < 4; ++ni)
            bvv[ni] = *(const bf16x8*)&Bs[(wn * 64 + ni * 16 + ln15) * 32 + hi * 8];
        for (int mi = 0; mi < 4; ++mi)
            for (int ni = 0; ni < 4; ++ni)
                acc[mi][ni] = __builtin_amdgcn_mfma_f32_16x16x32_bf16(av[mi], bvv[ni], acc[mi][ni], 0, 0, 0);
        asm volatile("s_waitcnt lgkmcnt(0)" ::: "memory");
        __builtin_amdgcn_s_barrier();
    }
    float* eps = (float*)lds;
    float bb[4];
#pragma unroll
    for (int ni = 0; ni < 4; ++ni) bb[ni] = bo[n0 + wn * 64 + ni * 16 + ln15];
    for (int mi = 0; mi < 4; ++mi) {
        __syncthreads();
#pragma unroll
        for (int ni = 0; ni < 4; ++ni)
#pragma unroll
            for (int r = 0; r < 4; ++r)
                eps[(wm * 16 + hi * 4 + r) * 256 + wn * 64 + ni * 16 + ln15] = acc[mi][ni][r] + bb[ni];
        __syncthreads();
#pragma unroll
        for (int k = 0; k < 4; ++k) {
            int idx = k * 512 + tid;
            int l = idx >> 6, c4 = idx & 63;
            int m = m0 + (l >> 4) * 64 + mi * 16 + (l & 15);
            int t = m >> 6, b = m & 63;
            float4 v = *(float4*)&eps[l * 256 + c4 * 4];
            if (BF16OUT) {
                ushort4 o;
                o.x = f2bf(v.x); o.y = f2bf(v.y); o.z = f2bf(v.z); o.w = f2bf(v.w);
                *(ushort4*)&scr[((size_t)(b * Tsz + t)) * Vsz + n0 + c4 * 4] = o;
            } else {
                *(float4*)&out[((size_t)(b * Tsz + t)) * Vsz + n0 + c4 * 4] = v;
            }
            float e = __expf(v.x) + __expf(v.y) + __expf(v.z) + __expf(v.w);
            for (int off = 32; off; off >>= 1) e += __shfl_down(e, off);
            if (lane == 0) atomicAdd(&sumexp[(m & 63) * Tsz + (m >> 6)], e);
        }
    }
}

// ---------------- log-softmax kernels ----------------
__global__ void sub_kernel(float* __restrict__ out, const float* __restrict__ sumexp) {
    const int total4 = (Bsz * Tsz * Vsz) / 4;
    float4* o4 = (float4*)out;
    for (int i = blockIdx.x * blockDim.x + threadIdx.x; i < total4; i += gridDim.x * blockDim.x) {
        float l = __logf(sumexp[i / (Vsz / 4)]);
        float4 v = o4[i];
        v.x -= l; v.y -= l; v.z -= l; v.w -= l;
        o4[i] = v;
    }
}

__global__ void sub_bf16_kernel(const u16* __restrict__ scr, const float* __restrict__ sumexp,
                                float* __restrict__ out) {
    const int total8 = (Bsz * Tsz * Vsz) / 8;
    for (int i = blockIdx.x * blockDim.x + threadIdx.x; i < total8; i += gridDim.x * blockDim.x) {
        float l = __logf(sumexp[i / (Vsz / 8)]);
        uint4 v = *(const uint4*)&scr[(size_t)i * 8];
        float4 a, b;
        a.x = bf2f((u16)v.x) - l;        a.y = bf2f((u16)(v.x >> 16)) - l;
        a.z = bf2f((u16)v.y) - l;        a.w = bf2f((u16)(v.y >> 16)) - l;
        b.x = bf2f((u16)v.z) - l;        b.y = bf2f((u16)(v.z >> 16)) - l;
        b.z = bf2f((u16)v.w) - l;        b.w = bf2f((u16)(v.w >> 16)) - l;
        *(float4*)&out[(size_t)i * 8] = a;
        *(float4*)&out[(size_t)i * 8 + 4] = b;
    }
}

extern "C" void kernel_launch(void* const* d_in, const int* in_sizes, int n_in,
                              void* d_out, int out_size, void* d_ws, size_t ws_size,
                              hipStream_t stream) {
    const float* enc   = (const float*)d_in[0];
    const float* ehid  = (const float*)d_in[1];
    const int*   target= (const int*)d_in[2];
    const float* emb   = (const float*)d_in[3];
    const float* Wa    = (const float*)d_in[4];
    const float* ba    = (const float*)d_in[5];
    const float* Ua    = (const float*)d_in[6];
    const float* bu    = (const float*)d_in[7];
    const float* va    = (const float*)d_in[8];
    const float* bv    = (const float*)d_in[9];
    const float* w_ih  = (const float*)d_in[10];
    const float* b_ih  = (const float*)d_in[11];
    const float* w_hh  = (const float*)d_in[12];
    const float* b_hh  = (const float*)d_in[13];
    const float* Wo    = (const float*)d_in[14];
    const float* bo    = (const float*)d_in[15];
    float* out = (float*)d_out;

    char* w = (char*)d_ws;
    float* uak    = (float*)w; w += (size_t)4096 * 512 * 4;           // 8 MB
    float* sumexp = (float*)w; w += 8192;
    unsigned* bar = (unsigned*)w; w += (size_t)NMAIL * 128;           // mailboxes (640 KB)
    u16* xbuf     = (u16*)w;   w += (size_t)Tsz * Bsz * 1024 * 2;     // 4 MB
    u16* Abf      = (u16*)w;   w += (size_t)Tsz * Bsz * Hsz * 2;      // 2 MB
    u16* h0bf     = (u16*)w;   w += (size_t)Bsz * Hsz * 2;
    u16* partials = (u16*)w;   w += (size_t)32 * Bsz * Hsz * 2;       // 2 MB
    u16* Wabf     = (u16*)w;   w += (size_t)Hsz * Hsz * 2;
    u16* encbf    = (u16*)w;   w += (size_t)4096 * 512 * 2;
    u16* Uabf     = (u16*)w;   w += (size_t)Hsz * Hsz * 2;
    u16* wihbf    = (u16*)w;   w += (size_t)1536 * 1024 * 2;
    u16* whhbf    = (u16*)w;   w += (size_t)1536 * 512 * 2;
    u16* Wobf     = (u16*)w;   w += (size_t)Vsz * 512 * 2;            // 32.77 MB
    u16* scrbf    = (u16*)w;   w += (size_t)Bsz * Tsz * Vsz * 2;      // 131 MB
    const int use_bf16 = (ws_size >= (size_t)(w - (char*)d_ws));

    // prep also zeroes bar + sumexp (dispatch-end release makes them visible to coop)
    prep_kernel<<<2048, 256, 0, stream>>>(enc, Ua, Wa, w_ih, w_hh, ehid, target, emb,
                                          encbf, Uabf, Wabf, wihbf, whhbf, h0bf, xbuf,
                                          bar, sumexp);

    // Ua_keys = enc @ Ua.T + bu   (M=4096, N=512, K=512)
    gemm_bt<<<dim3(32, 4), 256, 0, stream>>>(encbf, Uabf, bu, uak, 4096, 512, 512);

    // recurrence (96 blocks) + Wo conversion (160 blocks), 1 block/CU
    coop_kernel<<<NTOT, 512, 0, stream>>>(uak, xbuf, Abf, h0bf, wihbf, whhbf,
                                          Wabf, enc, va, bv, ba, b_ih, b_hh,
                                          ehid, Wo, Wobf, out, partials, bar);

    // logits = H @ Wo.T + bo  (M=2048, N=32000, K=512), 128x256 tiles
    if (use_bf16) {
        gemm_logits<1><<<2000, 512, 0, stream>>>(Abf, Wobf, bo, out, scrbf, sumexp);
        sub_bf16_kernel<<<4096, 256, 0, stream>>>(scrbf, sumexp, out);
    } else {
        gemm_logits<0><<<2000, 512, 0, stream>>>(Abf, Wobf, bo, out, scrbf, sumexp);
        sub_kernel<<<2048, 256, 0, stream>>>(out, sumexp);
    }
}

// Round 17
// 802.582 us; speedup vs baseline: 1.0408x; 1.0062x over previous
//
#include <hip/hip_runtime.h>

typedef unsigned short u16;
typedef __bf16 bf16x8 __attribute__((ext_vector_type(8)));
typedef float f32x4 __attribute__((ext_vector_type(4)));

#define Bsz 64
#define Ssz 64
#define Tsz 32
#define Hsz 512
#define Vsz 32000
#define NCONV 160
#define NTOT 256

// mailbox flag regions (slot = 128B = 32 u32)
#define MAIL_BG 0
#define MAIL_GB 2048
#define MAIL_GG 4096
#define NMAIL 5120

static __device__ inline u16 f2bf(float f) {
    union { float f; unsigned u; } v; v.f = f;
    unsigned u = v.u;
    unsigned r = (u + 0x7FFFu + ((u >> 16) & 1u)) >> 16;
    return (u16)r;
}
static __device__ inline float bf2f(u16 v) {
    union { unsigned u; float f; } x; x.u = ((unsigned)v) << 16; return x.f;
}
static __device__ inline float tanh_fast(float x) {
    float e = __expf(2.f * x);
    return 1.f - 2.f / (e + 1.f);
}
static __device__ inline void st_u32(unsigned* p, unsigned v) {
    __hip_atomic_store(p, v, __ATOMIC_RELAXED, __HIP_MEMORY_SCOPE_AGENT);
}
static __device__ inline unsigned ld_u32(const unsigned* p) {
    return __hip_atomic_load(p, __ATOMIC_RELAXED, __HIP_MEMORY_SCOPE_AGENT);
}
static __device__ inline void cv4(const float* __restrict__ s, u16* __restrict__ d, int j4) {
    float4 v = *(const float4*)&s[(size_t)j4 * 4];
    ushort4 o;
    o.x = f2bf(v.x); o.y = f2bf(v.y); o.z = f2bf(v.z); o.w = f2bf(v.w);
    *(ushort4*)&d[(size_t)j4 * 4] = o;
}

#define GLOAD_LDS16(g, l) \
    __builtin_amdgcn_global_load_lds((const __attribute__((address_space(1))) void*)(g), \
                                     (__attribute__((address_space(3))) void*)(l), 16, 0, 0)

// ---------------- prep (vectorized float4): weight conversion + embedding + zeroing -------
__global__ void prep_kernel(const float* __restrict__ enc, const float* __restrict__ Ua,
                            const float* __restrict__ Wa, const float* __restrict__ wih,
                            const float* __restrict__ whh, const float* __restrict__ ehid,
                            const int* __restrict__ target, const float* __restrict__ emb,
                            u16* __restrict__ encbf, u16* __restrict__ Uabf,
                            u16* __restrict__ Wabf, u16* __restrict__ wihbf,
                            u16* __restrict__ whhbf, u16* __restrict__ h0bf,
                            u16* __restrict__ xbuf,
                            unsigned* __restrict__ bar, float* __restrict__ sumexp) {
    // region sizes in float4/uint4 units
    const int q0 = 524288, q1 = 65536, q2 = 65536, q3 = 393216, q4 = 196608, q5 = 8192;
    const int q6 = 262144;          // embedding: (t,b) rows of 128 float4
    const int q7 = NMAIL * 8;       // bar: 40960 uint4
    const int q8 = 512;             // sumexp: 512 float4
    const int total = q0 + q1 + q2 + q3 + q4 + q5 + q6 + q7 + q8;
    for (int i = blockIdx.x * blockDim.x + threadIdx.x; i < total; i += gridDim.x * blockDim.x) {
        int j = i;
        if (j < q0) { cv4(enc, encbf, j); continue; } j -= q0;
        if (j < q1) { cv4(Ua, Uabf, j); continue; } j -= q1;
        if (j < q2) { cv4(Wa, Wabf, j); continue; } j -= q2;
        if (j < q3) { cv4(wih, wihbf, j); continue; } j -= q3;
        if (j < q4) { cv4(whh, whhbf, j); continue; } j -= q4;
        if (j < q5) { cv4(ehid, h0bf, j); continue; } j -= q5;
        if (j < q6) {
            int tb = j >> 7, k4 = j & 127;       // tb = t*64+b
            int t = tb >> 6, b = tb & 63;
            int id = (t == 0) ? 0 : target[b * Tsz + (t - 1)];
            float4 v = *(const float4*)&emb[(size_t)id * Hsz + k4 * 4];
            ushort4 o;
            o.x = f2bf(v.x); o.y = f2bf(v.y); o.z = f2bf(v.z); o.w = f2bf(v.w);
            *(ushort4*)&xbuf[(size_t)tb * 1024 + k4 * 4] = o;
            continue;
        } j -= q6;
        if (j < q7) { ((uint4*)bar)[j] = uint4{0u, 0u, 0u, 0u}; continue; } j -= q7;
        ((float4*)sumexp)[j] = float4{0.f, 0.f, 0.f, 0.f};
    }
}

// ---------------- bf16 MFMA GEMM (Ua_keys only) ----------------
__global__ __launch_bounds__(256) void gemm_bt(const u16* __restrict__ A, const u16* __restrict__ Bw,
                                               const float* __restrict__ bias, float* __restrict__ out,
                                               int M, int N, int K) {
    __shared__ __align__(16) u16 As[128 * 32];
    __shared__ __align__(16) u16 Bs[128 * 32];
    int m0 = blockIdx.x * 128, n0 = blockIdx.y * 128;
    int tid = threadIdx.x, lane = tid & 63, wid = tid >> 6;
    int wm = wid & 1, wn = wid >> 1;
    f32x4 acc[4][4] = {};
    for (int k0 = 0; k0 < K; k0 += 32) {
        int e0 = wid * 64 + lane;
        int e1 = e0 + 256;
        GLOAD_LDS16(&A[(size_t)(m0 + (e0 >> 2)) * K + k0 + (e0 & 3) * 8], (char*)As + wid * 1024);
        GLOAD_LDS16(&A[(size_t)(m0 + (e1 >> 2)) * K + k0 + (e1 & 3) * 8], (char*)As + 4096 + wid * 1024);
        GLOAD_LDS16(&Bw[(size_t)(n0 + (e0 >> 2)) * K + k0 + (e0 & 3) * 8], (char*)Bs + wid * 1024);
        GLOAD_LDS16(&Bw[(size_t)(n0 + (e1 >> 2)) * K + k0 + (e1 & 3) * 8], (char*)Bs + 4096 + wid * 1024);
        __syncthreads();
        bf16x8 av[4], bvv[4];
        for (int mi = 0; mi < 4; ++mi)
            av[mi] = *(const bf16x8*)&As[(wm * 64 + mi * 16 + (lane & 15)) * 32 + (lane >> 4) * 8];
        for (int ni = 0; ni < 4; ++ni)
            bvv[ni] = *(const bf16x8*)&Bs[(wn * 64 + ni * 16 + (lane & 15)) * 32 + (lane >> 4) * 8];
        for (int mi = 0; mi < 4; ++mi)
            for (int ni = 0; ni < 4; ++ni)
                acc[mi][ni] = __builtin_amdgcn_mfma_f32_16x16x32_bf16(av[mi], bvv[ni], acc[mi][ni], 0, 0, 0);
        __syncthreads();
    }
    for (int mi = 0; mi < 4; ++mi)
        for (int ni = 0; ni < 4; ++ni) {
            int n = n0 + wn * 64 + ni * 16 + (lane & 15);
            float bb = bias[n];
            for (int r = 0; r < 4; ++r) {
                int m = m0 + wm * 64 + mi * 16 + (lane >> 4) * 4 + r;
                out[(size_t)m * N + n] = acc[mi][ni][r] + bb;
            }
        }
}

// ---------------- persistent recurrence kernel (round-13 proven form: mailbox + partials) ----
__global__ __launch_bounds__(512, 1) void coop_kernel(
    const float* __restrict__ uak,
    u16* __restrict__ xbuf, u16* __restrict__ Abf,
    const u16* __restrict__ h0bf, const u16* __restrict__ wihbf, const u16* __restrict__ whhbf,
    const u16* __restrict__ Wabf, const float* __restrict__ enc,
    const float* __restrict__ va, const float* __restrict__ bv, const float* __restrict__ ba,
    const float* __restrict__ b_ih, const float* __restrict__ b_hh,
    const float* __restrict__ ehid,
    const float* __restrict__ Wo, u16* __restrict__ Wobf,
    float* __restrict__ out, u16* __restrict__ partials,
    unsigned* __restrict__ bar) {
    __shared__ __align__(16) char lds[149504];
    __shared__ float WhL[512];
    __shared__ float scL[64];
    __shared__ float vaL[512];

    const size_t HID_OFF = (size_t)Bsz * Tsz * Vsz;
    const size_t ATT_OFF = HID_OFF + (size_t)Bsz * Hsz;

    int tid = threadIdx.x, lane = tid & 63, wid = tid >> 6;
    int ln15 = lane & 15, hi = lane >> 4;
    int bx = blockIdx.x;

    unsigned* xbufU = (unsigned*)xbuf;
    unsigned* AbfU = (unsigned*)Abf;
    unsigned* partU = (unsigned*)partials;

    if (bx < 64) {
        // ================= B-blocks: Wh-sum + attention =================
        int b = bx;
        u16* uakL = (u16*)lds;
        u16* encL = (u16*)(lds + 65536);
        float* attL = (float*)(lds + 131072);   // 8 KB att stash
        for (int i = tid; i < Ssz * Hsz; i += 512) {
            uakL[i] = f2bf(uak[(size_t)b * Ssz * Hsz + i]);
            encL[i] = f2bf(enc[(size_t)b * Ssz * Hsz + i]);
        }
        vaL[tid] = va[tid];
        float bvv = bv[0];
        float ba_t = ba[tid];
        int halfsel = tid & 1;
        __syncthreads();

        for (int t = 0; t < Tsz; ++t) {
            if (tid < 32) {
                unsigned* p = &bar[(MAIL_GB + b * 32 + tid) * 32];
                while (ld_u32(p) < (unsigned)(t + 1)) asm volatile("s_sleep 1");
            }
            __syncthreads();
            {
                float acc = ba_t;
                const unsigned* pb = partU + (size_t)b * 256 + (tid >> 1);
#pragma unroll
                for (int g = 0; g < 32; ++g) {
                    unsigned pw = ld_u32(pb + (size_t)g * 16384);
                    acc += bf2f((u16)(halfsel ? (pw >> 16) : (pw & 0xffff)));
                }
                WhL[tid] = acc;
            }
            __syncthreads();
            for (int si = 0; si < 8; ++si) {
                int s = wid * 8 + si;
                float a = 0.f;
#pragma unroll
                for (int ji = 0; ji < 8; ++ji) {
                    int j = lane + ji * 64;
                    float x = WhL[j] + bf2f(uakL[s * 512 + j]);
                    a += tanh_fast(x) * vaL[j];
                }
                for (int off = 32; off; off >>= 1) a += __shfl_down(a, off);
                if (lane == 0) scL[s] = a + bvv;
            }
            __syncthreads();
            if (wid == 0) {
                float x = scL[lane];
                float mx = x;
                for (int off = 32; off; off >>= 1) mx = fmaxf(mx, __shfl_xor(mx, off));
                float e = __expf(x - mx);
                float sm = e;
                for (int off = 32; off; off >>= 1) sm += __shfl_xor(sm, off);
                float at = e / sm;
                scL[lane] = at;
                attL[t * 64 + lane] = at;
            }
            __syncthreads();
            float c = 0.f;
            for (int s = 0; s < Ssz; ++s)
                c += scL[s] * bf2f(encL[s * 512 + tid]);
            unsigned me = (unsigned)f2bf(c);
            unsigned other = __shfl_xor(me, 1);
            if ((tid & 1) == 0)
                st_u32(&xbufU[((size_t)t * Bsz + b) * 512 + 256 + (tid >> 1)], me | (other << 16));
            asm volatile("s_waitcnt vmcnt(0)" ::: "memory");
            __syncthreads();
            if (tid < 32) st_u32(&bar[(MAIL_BG + tid * 64 + b) * 32], (unsigned)(t + 1));
        }
        __syncthreads();
        for (int i = tid; i < Tsz * Ssz; i += 512)
            out[ATT_OFF + (size_t)b * (Tsz * Ssz) + i] = attL[i];
    } else if (bx < 96) {
        // ================= G-blocks: GRU + Wh-partials =================
        int g = bx - 64, jbase = g * 16;
        u16* hsl = (u16*)(lds + 147456);
        for (int i = tid; i < 6144; i += 512) {
            int row = i >> 7, c16 = i & 127;
            int Rg = (row >> 4) * 512 + jbase + (row & 15);
            uint4 v = *(const uint4*)&wihbf[(size_t)Rg * 1024 + c16 * 8];
            *(uint4*)(lds + row * 2048 + ((c16 * 16) ^ ((row & 7) << 4))) = v;
        }
        for (int i = tid; i < 3072; i += 512) {
            int row = i >> 6, c16 = i & 63;
            int Rg = (row >> 4) * 512 + jbase + (row & 15);
            uint4 v = *(const uint4*)&whhbf[(size_t)Rg * 512 + c16 * 8];
            *(uint4*)(lds + 98304 + row * 1024 + ((c16 * 16) ^ ((row & 7) << 4))) = v;
        }
        const char* wih_l = lds;
        const char* whh_l = lds + 98304;
        int j = jbase + ln15;
        float bir = b_ih[j] + b_hh[j];
        float biz = b_ih[512 + j] + b_hh[512 + j];
        float bin = b_ih[1024 + j];
        float bhn = b_hh[1024 + j];
        float hp0 = 0.f, hp1 = 0.f, hp2 = 0.f, hp3 = 0.f;
        if (wid < 4) {
            int m = wid;
            hp0 = ehid[(size_t)(m * 16 + hi * 4 + 0) * Hsz + j];
            hp1 = ehid[(size_t)(m * 16 + hi * 4 + 1) * Hsz + j];
            hp2 = ehid[(size_t)(m * 16 + hi * 4 + 2) * Hsz + j];
            hp3 = ehid[(size_t)(m * 16 + hi * 4 + 3) * Hsz + j];
        }
        int swz = (ln15 & 7) << 4;
        bf16x8 zfr = {};
        bf16x8 wfrag[4];
#pragma unroll
        for (int i = 0; i < 4; ++i) {
            int jp = (wid * 4 + i) * 16 + ln15;
            wfrag[i] = (hi < 2) ? *(const bf16x8*)&Wabf[(size_t)jp * 512 + jbase + hi * 8] : zfr;
        }
        for (int i = tid; i < 1024; i += 512)
            hsl[i] = h0bf[(size_t)(i >> 4) * 512 + jbase + (i & 15)];
        __syncthreads();
#pragma unroll
        for (int mt = 0; mt < 4; ++mt) {
            bf16x8 af = (hi < 2) ? *(const bf16x8*)&hsl[(mt * 16 + ln15) * 16 + hi * 8] : zfr;
#pragma unroll
            for (int i = 0; i < 4; ++i) {
                f32x4 pacc = {};
                pacc = __builtin_amdgcn_mfma_f32_16x16x32_bf16(af, wfrag[i], pacc, 0, 0, 0);
                int n0 = (wid * 4 + i) * 16;
#pragma unroll
                for (int r = 0; r < 4; ++r) {
                    int b = mt * 16 + hi * 4 + r;
                    unsigned me = (unsigned)f2bf(pacc[r]);
                    unsigned other = __shfl_xor(me, 1);
                    if ((ln15 & 1) == 0)
                        st_u32(&partU[((size_t)g * 64 + b) * 256 + ((n0 + ln15) >> 1)], me | (other << 16));
                }
            }
        }
        asm volatile("s_waitcnt vmcnt(0)" ::: "memory");
        __syncthreads();
        if (tid < 64) st_u32(&bar[(MAIL_GB + tid * 32 + g) * 32], 1u);
        else if (tid < 96) st_u32(&bar[(MAIL_GG + (tid - 64) * 32 + g) * 32], 1u);

        for (int t = 0; t < Tsz; ++t) {
            const u16* hbt = t ? (Abf + (size_t)(t - 1) * Bsz * Hsz) : h0bf;
            f32x4 ar = {}, az = {}, ain = {}, ahn = {};
            if (wid < 4) {
                int m = wid;
#pragma unroll 8
                for (int k0 = 0; k0 < 16; ++k0) {
                    bf16x8 a = *(const bf16x8*)&xbuf[((size_t)t * Bsz + m * 16 + ln15) * 1024 + k0 * 32 + hi * 8];
                    int byteIn = k0 * 64 + hi * 16;
                    bf16x8 b0 = *(const bf16x8*)(wih_l + (0 + ln15) * 2048 + (byteIn ^ swz));
                    bf16x8 b1 = *(const bf16x8*)(wih_l + (16 + ln15) * 2048 + (byteIn ^ swz));
                    bf16x8 b2 = *(const bf16x8*)(wih_l + (32 + ln15) * 2048 + (byteIn ^ swz));
                    ar = __builtin_amdgcn_mfma_f32_16x16x32_bf16(a, b0, ar, 0, 0, 0);
                    az = __builtin_amdgcn_mfma_f32_16x16x32_bf16(a, b1, az, 0, 0, 0);
                    ain = __builtin_amdgcn_mfma_f32_16x16x32_bf16(a, b2, ain, 0, 0, 0);
                }
            }
            if (tid < 32) {
                unsigned* p = &bar[(MAIL_GG + g * 32 + tid) * 32];
                while (ld_u32(p) < (unsigned)(t + 1)) asm volatile("s_sleep 1");
            }
            __syncthreads();
            if (wid < 4) {
                int m = wid;
#pragma unroll 8
                for (int k0 = 0; k0 < 16; ++k0) {
                    bf16x8 a = *(const bf16x8*)&hbt[(size_t)(m * 16 + ln15) * 512 + k0 * 32 + hi * 8];
                    int byteIn = k0 * 64 + hi * 16;
                    bf16x8 b0 = *(const bf16x8*)(whh_l + (0 + ln15) * 1024 + (byteIn ^ swz));
                    bf16x8 b1 = *(const bf16x8*)(whh_l + (16 + ln15) * 1024 + (byteIn ^ swz));
                    bf16x8 b2 = *(const bf16x8*)(whh_l + (32 + ln15) * 1024 + (byteIn ^ swz));
                    ar = __builtin_amdgcn_mfma_f32_16x16x32_bf16(a, b0, ar, 0, 0, 0);
                    az = __builtin_amdgcn_mfma_f32_16x16x32_bf16(a, b1, az, 0, 0, 0);
                    ahn = __builtin_amdgcn_mfma_f32_16x16x32_bf16(a, b2, ahn, 0, 0, 0);
                }
                unsigned* p = &bar[(MAIL_BG + g * 64 + wid * 16 + ln15) * 32];
                while (ld_u32(p) < (unsigned)(t + 1)) asm volatile("s_sleep 1");
#pragma unroll 8
                for (int k0 = 16; k0 < 32; ++k0) {
                    bf16x8 a = *(const bf16x8*)&xbuf[((size_t)t * Bsz + m * 16 + ln15) * 1024 + k0 * 32 + hi * 8];
                    int byteIn = k0 * 64 + hi * 16;
                    bf16x8 b0 = *(const bf16x8*)(wih_l + (0 + ln15) * 2048 + (byteIn ^ swz));
                    bf16x8 b1 = *(const bf16x8*)(wih_l + (16 + ln15) * 2048 + (byteIn ^ swz));
                    bf16x8 b2 = *(const bf16x8*)(wih_l + (32 + ln15) * 2048 + (byteIn ^ swz));
                    ar = __builtin_amdgcn_mfma_f32_16x16x32_bf16(a, b0, ar, 0, 0, 0);
                    az = __builtin_amdgcn_mfma_f32_16x16x32_bf16(a, b1, az, 0, 0, 0);
                    ain = __builtin_amdgcn_mfma_f32_16x16x32_bf16(a, b2, ain, 0, 0, 0);
                }
                float hpv[4] = {hp0, hp1, hp2, hp3};
#pragma unroll
                for (int r = 0; r < 4; ++r) {
                    int b = m * 16 + hi * 4 + r;
                    float rg = 1.f / (1.f + __expf(-(ar[r] + bir)));
                    float zg = 1.f / (1.f + __expf(-(az[r] + biz)));
                    float ng = tanh_fast(ain[r] + bin + rg * (ahn[r] + bhn));
                    float hv = (1.f - zg) * ng + zg * hpv[r];
                    hpv[r] = hv;
                    u16 hb = f2bf(hv);
                    unsigned me = (unsigned)hb;
                    unsigned other = __shfl_xor(me, 1);
                    if ((ln15 & 1) == 0)
                        st_u32(&AbfU[((size_t)t * Bsz + b) * 256 + (j >> 1)], me | (other << 16));
                    hsl[b * 16 + ln15] = hb;
                    if (t == Tsz - 1) out[HID_OFF + (size_t)b * 512 + j] = hv;
                }
                hp0 = hpv[0]; hp1 = hpv[1]; hp2 = hpv[2]; hp3 = hpv[3];
            }
            __syncthreads();
#pragma unroll
            for (int mt = 0; mt < 4; ++mt) {
                bf16x8 af = (hi < 2) ? *(const bf16x8*)&hsl[(mt * 16 + ln15) * 16 + hi * 8] : zfr;
#pragma unroll
                for (int i = 0; i < 4; ++i) {
                    f32x4 pacc = {};
                    pacc = __builtin_amdgcn_mfma_f32_16x16x32_bf16(af, wfrag[i], pacc, 0, 0, 0);
                    int n0 = (wid * 4 + i) * 16;
#pragma unroll
                    for (int r = 0; r < 4; ++r) {
                        int b = mt * 16 + hi * 4 + r;
                        unsigned me = (unsigned)f2bf(pacc[r]);
                        unsigned other = __shfl_xor(me, 1);
                        if ((ln15 & 1) == 0)
                            st_u32(&partU[((size_t)g * 64 + b) * 256 + ((n0 + ln15) >> 1)], me | (other << 16));
                    }
                }
            }
            asm volatile("s_waitcnt vmcnt(0)" ::: "memory");
            __syncthreads();
            if (tid < 64) st_u32(&bar[(MAIL_GB + tid * 32 + g) * 32], (unsigned)(t + 2));
            else if (tid < 96) st_u32(&bar[(MAIL_GG + (tid - 64) * 32 + g) * 32], (unsigned)(t + 2));
        }
    } else {
        // ================= converter blocks: Wo f32 -> bf16 (plain stores) =============
        const float4* W4 = (const float4*)Wo;
        for (int i = (bx - 96) * 512 + tid; i < (Vsz * Hsz) / 4; i += NCONV * 512) {
            float4 v = W4[i];
            ushort4 o;
            o.x = f2bf(v.x); o.y = f2bf(v.y); o.z = f2bf(v.z); o.w = f2bf(v.w);
            *(ushort4*)&Wobf[(size_t)i * 4] = o;
        }
    }
}

// ---------------- logits GEMM: 128x256 tiles, dbuf + counted vmcnt,
//                  L2-locality job map: 16 consecutive blocks share one Wo panel ----------------
template <int BF16OUT>
__global__ __launch_bounds__(512) void gemm_logits(const u16* __restrict__ Abf, const u16* __restrict__ Wobf,
                                                   const float* __restrict__ bo, float* __restrict__ out,
                                                   u16* __restrict__ scr, float* __restrict__ sumexp) {
    __shared__ __align__(16) char lds[49152];
    char* As0 = lds;
    char* Bs0 = lds + 8192;
    char* As1 = lds + 24576;
    char* Bs1 = lds + 32768;
    int tid = threadIdx.x, lane = tid & 63, wid = tid >> 6;
    int ln15 = lane & 15, hi = lane >> 4;
    int wm = wid & 1, wn = wid >> 1;
    int job = blockIdx.x;
    int m0 = (job & 15) * 128, n0 = (job >> 4) * 256;   // panel-sharers adjacent
    f32x4 acc[4][4] = {};
    {
        int e0 = wid * 64 + lane, r = e0 >> 2, c8 = (e0 & 3) * 8;
        GLOAD_LDS16(&Abf[(size_t)(m0 + r) * 512 + c8], As0 + wid * 1024);
        GLOAD_LDS16(&Wobf[(size_t)(n0 + r) * 512 + c8], Bs0 + wid * 1024);
        GLOAD_LDS16(&Wobf[(size_t)(n0 + 128 + r) * 512 + c8], Bs0 + 8192 + wid * 1024);
    }
#pragma unroll 2
    for (int ks = 0; ks < 16; ++ks) {
        const u16* As = (const u16*)((ks & 1) ? As1 : As0);
        const u16* Bs = (const u16*)((ks & 1) ? Bs1 : Bs0);
        if (ks < 15) {
            char* Asn = (ks & 1) ? As0 : As1;
            char* Bsn = (ks & 1) ? Bs0 : Bs1;
            int e0 = wid * 64 + lane, r = e0 >> 2, c8 = (e0 & 3) * 8;
            int k0 = (ks + 1) * 32;
            GLOAD_LDS16(&Abf[(size_t)(m0 + r) * 512 + k0 + c8], Asn + wid * 1024);
            GLOAD_LDS16(&Wobf[(size_t)(n0 + r) * 512 + k0 + c8], Bsn + wid * 1024);
            GLOAD_LDS16(&Wobf[(size_t)(n0 + 128 + r) * 512 + k0 + c8], Bsn + 8192 + wid * 1024);
            asm volatile("s_waitcnt vmcnt(3)" ::: "memory");
        } else {
            asm volatile("s_waitcnt vmcnt(0)" ::: "memory");
        }
        __builtin_amdgcn_s_barrier();
        bf16x8 av[4], bvv[4];
        for (int mi = 0; mi < 4; ++mi)
            av[mi] = *(const bf16x8*)&As[(wm * 64 + mi * 16 + ln15) * 32 + hi * 8];
        for (int ni = 0; ni < 4; ++ni)
            bvv[ni] = *(const bf16x8*)&Bs[(wn * 64 + ni * 16 + ln15) * 32 + hi * 8];
        for (int mi = 0; mi < 4; ++mi)
            for (int ni = 0; ni < 4; ++ni)
                acc[mi][ni] = __builtin_amdgcn_mfma_f32_16x16x32_bf16(av[mi], bvv[ni], acc[mi][ni], 0, 0, 0);
        asm volatile("s_waitcnt lgkmcnt(0)" ::: "memory");
        __builtin_amdgcn_s_barrier();
    }
    float* eps = (float*)lds;
    float bb[4];
#pragma unroll
    for (int ni = 0; ni < 4; ++ni) bb[ni] = bo[n0 + wn * 64 + ni * 16 + ln15];
    for (int mi = 0; mi < 4; ++mi) {
        __syncthreads();
#pragma unroll
        for (int ni = 0; ni < 4; ++ni)
#pragma unroll
            for (int r = 0; r < 4; ++r)
                eps[(wm * 16 + hi * 4 + r) * 256 + wn * 64 + ni * 16 + ln15] = acc[mi][ni][r] + bb[ni];
        __syncthreads();
#pragma unroll
        for (int k = 0; k < 4; ++k) {
            int idx = k * 512 + tid;
            int l = idx >> 6, c4 = idx & 63;
            int m = m0 + (l >> 4) * 64 + mi * 16 + (l & 15);
            int t = m >> 6, b = m & 63;
            float4 v = *(float4*)&eps[l * 256 + c4 * 4];
            if (BF16OUT) {
                ushort4 o;
                o.x = f2bf(v.x); o.y = f2bf(v.y); o.z = f2bf(v.z); o.w = f2bf(v.w);
                *(ushort4*)&scr[((size_t)(b * Tsz + t)) * Vsz + n0 + c4 * 4] = o;
            } else {
                *(float4*)&out[((size_t)(b * Tsz + t)) * Vsz + n0 + c4 * 4] = v;
            }
            float e = __expf(v.x) + __expf(v.y) + __expf(v.z) + __expf(v.w);
            for (int off = 32; off; off >>= 1) e += __shfl_down(e, off);
            if (lane == 0) atomicAdd(&sumexp[(m & 63) * Tsz + (m >> 6)], e);
        }
    }
}

// ---------------- log-softmax kernels ----------------
__global__ void sub_kernel(float* __restrict__ out, const float* __restrict__ sumexp) {
    const int total4 = (Bsz * Tsz * Vsz) / 4;
    float4* o4 = (float4*)out;
    for (int i = blockIdx.x * blockDim.x + threadIdx.x; i < total4; i += gridDim.x * blockDim.x) {
        float l = __logf(sumexp[i / (Vsz / 4)]);
        float4 v = o4[i];
        v.x -= l; v.y -= l; v.z -= l; v.w -= l;
        o4[i] = v;
    }
}

__global__ void sub_bf16_kernel(const u16* __restrict__ scr, const float* __restrict__ sumexp,
                                float* __restrict__ out) {
    const int total8 = (Bsz * Tsz * Vsz) / 8;
    for (int i = blockIdx.x * blockDim.x + threadIdx.x; i < total8; i += gridDim.x * blockDim.x) {
        float l = __logf(sumexp[i / (Vsz / 8)]);
        uint4 v = *(const uint4*)&scr[(size_t)i * 8];
        float4 a, b;
        a.x = bf2f((u16)v.x) - l;        a.y = bf2f((u16)(v.x >> 16)) - l;
        a.z = bf2f((u16)v.y) - l;        a.w = bf2f((u16)(v.y >> 16)) - l;
        b.x = bf2f((u16)v.z) - l;        b.y = bf2f((u16)(v.z >> 16)) - l;
        b.z = bf2f((u16)v.w) - l;        b.w = bf2f((u16)(v.w >> 16)) - l;
        *(float4*)&out[(size_t)i * 8] = a;
        *(float4*)&out[(size_t)i * 8 + 4] = b;
    }
}

extern "C" void kernel_launch(void* const* d_in, const int* in_sizes, int n_in,
                              void* d_out, int out_size, void* d_ws, size_t ws_size,
                              hipStream_t stream) {
    const float* enc   = (const float*)d_in[0];
    const float* ehid  = (const float*)d_in[1];
    const int*   target= (const int*)d_in[2];
    const float* emb   = (const float*)d_in[3];
    const float* Wa    = (const float*)d_in[4];
    const float* ba    = (const float*)d_in[5];
    const float* Ua    = (const float*)d_in[6];
    const float* bu    = (const float*)d_in[7];
    const float* va    = (const float*)d_in[8];
    const float* bv    = (const float*)d_in[9];
    const float* w_ih  = (const float*)d_in[10];
    const float* b_ih  = (const float*)d_in[11];
    const float* w_hh  = (const float*)d_in[12];
    const float* b_hh  = (const float*)d_in[13];
    const float* Wo    = (const float*)d_in[14];
    const float* bo    = (const float*)d_in[15];
    float* out = (float*)d_out;

    char* w = (char*)d_ws;
    float* uak    = (float*)w; w += (size_t)4096 * 512 * 4;           // 8 MB
    float* sumexp = (float*)w; w += 8192;
    unsigned* bar = (unsigned*)w; w += (size_t)NMAIL * 128;           // mailboxes (640 KB)
    u16* xbuf     = (u16*)w;   w += (size_t)Tsz * Bsz * 1024 * 2;     // 4 MB
    u16* Abf      = (u16*)w;   w += (size_t)Tsz * Bsz * Hsz * 2;      // 2 MB
    u16* h0bf     = (u16*)w;   w += (size_t)Bsz * Hsz * 2;
    u16* partials = (u16*)w;   w += (size_t)32 * Bsz * Hsz * 2;       // 2 MB
    u16* Wabf     = (u16*)w;   w += (size_t)Hsz * Hsz * 2;
    u16* encbf    = (u16*)w;   w += (size_t)4096 * 512 * 2;
    u16* Uabf     = (u16*)w;   w += (size_t)Hsz * Hsz * 2;
    u16* wihbf    = (u16*)w;   w += (size_t)1536 * 1024 * 2;
    u16* whhbf    = (u16*)w;   w += (size_t)1536 * 512 * 2;
    u16* Wobf     = (u16*)w;   w += (size_t)Vsz * 512 * 2;            // 32.77 MB
    u16* scrbf    = (u16*)w;   w += (size_t)Bsz * Tsz * Vsz * 2;      // 131 MB
    const int use_bf16 = (ws_size >= (size_t)(w - (char*)d_ws));

    // prep (vectorized) also zeroes bar + sumexp
    prep_kernel<<<2048, 256, 0, stream>>>(enc, Ua, Wa, w_ih, w_hh, ehid, target, emb,
                                          encbf, Uabf, Wabf, wihbf, whhbf, h0bf, xbuf,
                                          bar, sumexp);

    // Ua_keys = enc @ Ua.T + bu   (M=4096, N=512, K=512)
    gemm_bt<<<dim3(32, 4), 256, 0, stream>>>(encbf, Uabf, bu, uak, 4096, 512, 512);

    // recurrence (96 blocks) + Wo conversion (160 blocks), 1 block/CU
    coop_kernel<<<NTOT, 512, 0, stream>>>(uak, xbuf, Abf, h0bf, wihbf, whhbf,
                                          Wabf, enc, va, bv, ba, b_ih, b_hh,
                                          ehid, Wo, Wobf, out, partials, bar);

    // logits = H @ Wo.T + bo  (M=2048, N=32000, K=512), 128x256 tiles
    if (use_bf16) {
        gemm_logits<1><<<2000, 512, 0, stream>>>(Abf, Wobf, bo, out, scrbf, sumexp);
        sub_bf16_kernel<<<4096, 256, 0, stream>>>(scrbf, sumexp, out);
    } else {
        gemm_logits<0><<<2000, 512, 0, stream>>>(Abf, Wobf, bo, out, scrbf, sumexp);
        sub_kernel<<<2048, 256, 0, stream>>>(out, sumexp);
    }
}